// Round 17
// baseline (39.444 us; speedup 1.0000x reference)
//
#include <hip/hip_runtime.h>

#define IN_F   256
#define OUT_F  256
#define NINT   15
#define IHALF  128            // input features per block (IN-dim split in 2)
#define NC4    (IHALF * NINT) // float4 coeff entries per block = 1920

typedef const __attribute__((address_space(1))) void gvoid_t;
typedef __attribute__((address_space(3))) void lvoid_t;

// --- bin 8 evals (groups of 8 features); exact XLA-f32-linspace semantics ---
__device__ __forceinline__ void kbin8(const float* __restrict__ wrow,
                                      const float4* __restrict__ xrow,
                                      int g, int* jj, float* dxv) {
    const float kD = 2.0f / 15.0f;                 // fl32(2/15), XLA delta bits
    float4 xv0 = xrow[2 * g], xv1 = xrow[2 * g + 1];
    float xs[8] = {xv0.x, xv0.y, xv0.z, xv0.w, xv1.x, xv1.y, xv1.z, xv1.w};
    #pragma unroll
    for (int e = 0; e < 8; ++e) {
        float wv = wrow[g * 8 + e];                // wave-uniform -> scalar s_load
        float wx = wv * xs[e];                     // ref's exact f32 product
        float xc = fminf(fmaxf(wx, -1.0f), 1.0f);
        float u  = __builtin_fmaf(xc, 7.5f, 7.4999f);  // down-biased floor guess
        int   i0 = (int)u;                         // ∈ [0,14]
        float f0 = (float)i0;
        float blo = __fadd_rn(__fmul_rn(f0, kD), -1.0f);                   // bp[i0]
        float bhi = __fadd_rn(__fmul_rn(__fadd_rn(f0, 1.0f), kD), -1.0f);  // bp[i0+1]
        bool  up = (xc >= bhi);                    // exact searchsorted(right)-1
        jj[e]  = i0 + (up ? 1 : 0);
        dxv[e] = xc - (up ? bhi : blo);            // ref's exact f32 sub
    }
}

__device__ __forceinline__ void kgather8(const float4* __restrict__ sc,
                                         int g, const int* jj, float4* c) {
    #pragma unroll
    for (int e = 0; e < 8; ++e)
        c[e] = sc[(g * 8 + e) * NINT + jj[e]];     // issued well before consumption
}

__device__ __forceinline__ void khorner8(const float4* c, const float* dxv,
                                         float& a0, float& a1, float& a2, float& a3) {
    #pragma unroll
    for (int e = 0; e < 8; ++e) {
        float dx = dxv[e];
        float y = __builtin_fmaf(__builtin_fmaf(__builtin_fmaf(
                      c[e].w, dx, c[e].z), dx, c[e].y), dx, c[e].x);
        switch (e & 3) { case 0: a0 += y; break; case 1: a1 += y; break;
                         case 2: a2 += y; break; default: a3 += y; }
    }
}

// R6 shape (512 thr, 2 blocks/CU) + software-pipelined gather (A/B ping-pong):
// gather(g) is issued, then horner(g-1) runs -> ~240 VALU cycles cover the LDS
// latency in-wave, breaking the all-waves-wait-together convoy.
__global__ __launch_bounds__(512, 4)
void kan_kernel(const float* __restrict__ x, const float* __restrict__ w,
                const float* __restrict__ bias, const float* __restrict__ coeffs,
                float* __restrict__ out)
{
    __shared__ float4 sc[NC4];          // 30720 B; no sw4 (w is on the scalar pipe)

    const int o = blockIdx.x >> 1, h = blockIdx.x & 1, b = threadIdx.x;

    const float4* gsrc = reinterpret_cast<const float4*>(coeffs)
                         + ((size_t)o * IN_F + h * IHALF) * NINT;
    #pragma unroll
    for (int k = 0; k < 4; ++k) {
        int t = b + k * 512;
        if (t < NC4)  // k==3: b<384 = 6 whole waves, wave-uniform predicate
            __builtin_amdgcn_global_load_lds((gvoid_t*)(gsrc + t), (lvoid_t*)(sc + t), 16, 0, 0);
    }
    const float* wrow = w + (size_t)o * IN_F + h * IHALF;
    const float4* xrow = reinterpret_cast<const float4*>(x + (size_t)b * IN_F + h * IHALF);
    __syncthreads();

    float a0 = 0.f, a1 = 0.f, a2 = 0.f, a3 = 0.f;
    int   jA[8], jB[8];
    float dA[8], dB[8];
    float4 cA[8], cB[8];

    // prologue: group 0 into A
    kbin8(wrow, xrow, 0, jA, dA);
    kgather8(sc, 0, jA, cA);

    #pragma unroll 1
    for (int t = 0; t < 7; ++t) {       // groups 1..14 in pairs
        int g1 = 2 * t + 1, g2 = 2 * t + 2;
        kbin8(wrow, xrow, g1, jB, dB);
        kgather8(sc, g1, jB, cB);       // B in flight...
        khorner8(cA, dA, a0, a1, a2, a3);   // ...while A is consumed
        kbin8(wrow, xrow, g2, jA, dA);
        kgather8(sc, g2, jA, cA);       // A in flight...
        khorner8(cB, dB, a0, a1, a2, a3);   // ...while B is consumed
    }
    // epilogue: group 15
    kbin8(wrow, xrow, 15, jB, dB);
    kgather8(sc, 15, jB, cB);
    khorner8(cA, dA, a0, a1, a2, a3);
    khorner8(cB, dB, a0, a1, a2, a3);

    float acc = (a0 + a1) + (a2 + a3);
    if (h == 0) acc += bias[o];
    // out zeroed by memset; exactly 2 commutative adds from exact 0 per element.
    atomicAdd(out + (size_t)b * OUT_F + o, acc);
}

extern "C" void kernel_launch(void* const* d_in, const int* in_sizes, int n_in,
                              void* d_out, int out_size, void* d_ws, size_t ws_size,
                              hipStream_t stream) {
    (void)d_ws; (void)ws_size;

    const float *x = nullptr, *wgt = nullptr, *bias = nullptr, *coeffs = nullptr;
    for (int i = 0; i < n_in; ++i) {
        switch (in_sizes[i]) {
            case 512 * 256:           x      = (const float*)d_in[i]; break;
            case 256 * 256:           wgt    = (const float*)d_in[i]; break;
            case 256:                 bias   = (const float*)d_in[i]; break;
            case 256 * 256 * 15 * 4:  coeffs = (const float*)d_in[i]; break;
            default: break;
        }
    }

    hipMemsetAsync(d_out, 0, (size_t)out_size * sizeof(float), stream);
    kan_kernel<<<2 * OUT_F, 512, 0, stream>>>(x, wgt, bias, coeffs, (float*)d_out);
}